// Round 7
// baseline (183.390 us; speedup 1.0000x reference)
//
#include <hip/hip_runtime.h>
#include <cstdint>

#define HW 4096

typedef __attribute__((ext_vector_type(8))) short bf16x8;
typedef __attribute__((ext_vector_type(4))) float f32x4;

__device__ __forceinline__ short f2bf(float f) {
    union { float f; uint32_t u; } v; v.f = f;
    uint32_t u = v.u;
    uint32_t r = (u + 0x7FFFu + ((u >> 16) & 1u)) >> 16;
    return (short)(r & 0xFFFFu);
}
__device__ __forceinline__ uint32_t cvtpk(float lo, float hi) {
    uint32_t r;
    asm("v_cvt_pk_bf16_f32 %0, %1, %2" : "=v"(r) : "v"(lo), "v"(hi));
    return r;
}
__device__ __forceinline__ float blo(uint32_t u) { return __uint_as_float(u << 16); }
__device__ __forceinline__ float bhi(uint32_t u) { return __uint_as_float(u & 0xFFFF0000u); }
__device__ __forceinline__ void glds16(const void* g, void* l) {
    __builtin_amdgcn_global_load_lds(
        (const __attribute__((address_space(1))) void*)g,
        (__attribute__((address_space(3))) void*)l, 16, 0, 0);
}

// ---------------------------------------------------------------------------
// Kernel 1: transpose x[b][c][hw] (fp32) -> xT[b][hw][c] (bf16).
// ---------------------------------------------------------------------------
__global__ __launch_bounds__(256) void k_xt(
    const float* __restrict__ x, unsigned short* __restrict__ xT)
{
    __shared__ unsigned short s[64][65];
    const int t = threadIdx.x, lane = t & 63, grp = t >> 6;
    const int hw0 = blockIdx.x * 64, c0 = blockIdx.y * 64, b = blockIdx.z;
#pragma unroll
    for (int j = 0; j < 16; ++j) {
        int cc = grp * 16 + j;
        float v = x[((size_t)(b * 256 + c0 + cc)) * HW + hw0 + lane];
        s[cc][lane] = (unsigned short)f2bf(v);
    }
    __syncthreads();
#pragma unroll
    for (int j = 0; j < 16; ++j) {
        int hw2 = grp * 16 + j;
        xT[((size_t)b * HW + hw0 + hw2) * 256 + c0 + lane] = s[lane][hw2];
    }
}

// ---------------------------------------------------------------------------
// Kernel 2 (merged): both weight conversions in one launch.
// a2r: FRAGMENT-CONTIGUOUS layout for k_fused's direct-from-L2 A-loads.
//   frag id f = (j*4 + ss)*16 + rg   (j = dg*9+tap 0..17, ss 0..3, rg 0..15)
//   a2r[f*512 + lane*8 + e] = w[o = rg*16 + (lane&15)]
//                              [k-chunk cch = ss*32 + (lane>>4)*8 + e]
// ---------------------------------------------------------------------------
__global__ __launch_bounds__(256) void k_wcvt_all(
    const float* __restrict__ weight, const float* __restrict__ w_off,
    short* __restrict__ a2r, short* __restrict__ wTb)
{
    int e = blockIdx.x * 256 + threadIdx.x;     // 737280 total
    if (e < 589824) {
        int el = e & 7;
        int lane = (e >> 3) & 63;
        int rg = (e >> 9) & 15;
        int ss = (e >> 13) & 3;
        int j = e >> 15;                        // 0..17
        int o = rg * 16 + (lane & 15);
        int cch = ss * 32 + (lane >> 4) * 8 + el;
        int dg = j / 9, tap = j - dg * 9;
        a2r[e] = f2bf(weight[o * 2304 + (dg * 128 + cch) * 9 + tap]);
    } else {
        int e2 = e - 589824;
        int o = e2 / 2304, r = e2 - o * 2304;
        int tap = r >> 8, c = r & 255;
        wTb[e2] = (o < 54) ? f2bf(w_off[(o * 256 + c) * 9 + tap]) : (short)0;
    }
}

// ---------------------------------------------------------------------------
// Kernel 3: offset conv as MFMA GEMM, split-K x4, software-pipelined.
// ---------------------------------------------------------------------------
__global__ __launch_bounds__(256, 4) void k_omgemm(
    const short* __restrict__ wTb, const unsigned short* __restrict__ xT,
    float* __restrict__ om2p)
{
    __shared__ short As[2][64 * 32];
    __shared__ short Bs[2][64 * 32];
    const int t = threadIdx.x;
    const int wid = __builtin_amdgcn_readfirstlane(t >> 6);
    const int lane = t & 63, quad = lane >> 4, l16 = lane & 15;
    const int n0 = blockIdx.x * 64, b = n0 >> 12;
    const int ks = blockIdx.y;          // 0..3 -> chunks ks*18 .. ks*18+17
    const int nr = t >> 2;
    const int ksh = (t & 3) * 8;
    const int px = (n0 + nr) & 4095, h = px >> 6, w = px & 63;
    const unsigned short* xb = xT + (size_t)b * HW * 256;
    const int cbase = ks * 18;

    auto loadB = [&](int c) -> uint4 {
        int tap = c >> 3, c0 = (c & 7) * 32;
        int hh = h + tap / 3 - 1, ww = w + tap % 3 - 1;
        uint4 bv = {0u, 0u, 0u, 0u};
        if (hh >= 0 && hh < 64 && ww >= 0 && ww < 64)
            bv = *(const uint4*)(xb + (size_t)(hh * 64 + ww) * 256 + c0 + ksh);
        return bv;
    };

    f32x4 acc[4];
#pragma unroll
    for (int i = 0; i < 4; ++i) acc[i] = (f32x4){0.f, 0.f, 0.f, 0.f};

    uint4 bv[2];
    bv[0] = loadB(cbase);
    glds16(wTb + (size_t)nr * 2304 + cbase * 32 + ksh, &As[0][t * 8]);
    *(uint4*)&Bs[0][t * 8] = bv[0];
    bv[1] = loadB(cbase + 1);

#pragma unroll 2
    for (int i = 0; i < 18; ++i) {
        const int p = i & 1;
        __syncthreads();
        if (i < 17) {
            glds16(wTb + (size_t)nr * 2304 + (cbase + i + 1) * 32 + ksh,
                   &As[1 - p][t * 8]);
            *(uint4*)&Bs[1 - p][t * 8] = bv[(i + 1) & 1];
        }
        if (i + 2 < 18) bv[i & 1] = loadB(cbase + i + 2);
        bf16x8 bf = *(const bf16x8*)&Bs[p][(wid * 16 + l16) * 32 + quad * 8];
#pragma unroll
        for (int mi = 0; mi < 4; ++mi) {
            bf16x8 af = *(const bf16x8*)&As[p][(mi * 16 + l16) * 32 + quad * 8];
            acc[mi] = __builtin_amdgcn_mfma_f32_16x16x32_bf16(af, bf, acc[mi], 0, 0, 0);
        }
    }
    const int n = n0 + wid * 16 + l16;
#pragma unroll
    for (int mi = 0; mi < 4; ++mi)
#pragma unroll
        for (int i = 0; i < 4; ++i)
            om2p[(size_t)(ks * 64 + mi * 16 + quad * 4 + i) * 16384 + n] = acc[mi][i];
}

// ---------------------------------------------------------------------------
// Kernel 5: sampling plan (sums 4 split-K partials).
// ---------------------------------------------------------------------------
__global__ __launch_bounds__(256) void k_plan(
    const float* __restrict__ om2p, const float* __restrict__ b_off,
    float4* __restrict__ planw, int4* __restrict__ plani)
{
    int e = blockIdx.x * 256 + threadIdx.x;      // 294912
    int n = e & 16383, s = e >> 14;
    int dg = s >= 9 ? 1 : 0, tap = s - dg * 9;
    int h = (n >> 6) & 63, w = n & 63;
    int cdy = dg * 18 + tap, cdx = cdy + 9, cms = 36 + dg * 9 + tap;
    float dy = b_off[cdy], dx = b_off[cdx], ms = b_off[cms];
#pragma unroll
    for (int cs = 0; cs < 4; ++cs) {
        const float* p = om2p + (size_t)cs * 64 * 16384;
        dy += p[(size_t)cdy * 16384 + n];
        dx += p[(size_t)cdx * 16384 + n];
        ms += p[(size_t)cms * 16384 + n];
    }
    ms = 1.f / (1.f + __expf(-ms));
    float py = dy + (float)(h + tap / 3 - 1);
    float qx = dx + (float)(w + tap % 3 - 1);
    float y0f = floorf(py), x0f = floorf(qx);
    float wy1 = py - y0f, wx1 = qx - x0f;
    float wy0 = 1.f - wy1, wx0 = 1.f - wx1;
    int y0 = (int)y0f, x0 = (int)x0f;
    int y1 = y0 + 1, x1 = x0 + 1;
    bool vy0 = (y0 >= 0) & (y0 < 64), vy1 = (y1 >= 0) & (y1 < 64);
    bool vx0 = (x0 >= 0) & (x0 < 64), vx1 = (x1 >= 0) & (x1 < 64);
    int cy0 = min(max(y0, 0), 63), cy1 = min(max(y1, 0), 63);
    int cx0 = min(max(x0, 0), 63), cx1 = min(max(x1, 0), 63);
    float4 wv;
    wv.x = (vy0 && vx0) ? wy0 * wx0 * ms : 0.f;
    wv.y = (vy0 && vx1) ? wy0 * wx1 * ms : 0.f;
    wv.z = (vy1 && vx0) ? wy1 * wx0 * ms : 0.f;
    wv.w = (vy1 && vx1) ? wy1 * wx1 * ms : 0.f;
    int4 iv = make_int4((cy0 * 64 + cx0) << 9, (cy0 * 64 + cx1) << 9,
                        (cy1 * 64 + cx0) << 9, (cy1 * 64 + cx1) << 9);
    planw[e] = wv;
    plani[e] = iv;
}

// ---------------------------------------------------------------------------
// Kernel 6: FUSED sampling + GEMM, A direct from L2 + A-REGISTER DOUBLE
// BUFFER. R6 structure (1024 thr, 16 waves, 256m x 64px, K=128/tap,
// 18 iters, LDS = Bs only 32 KB) with one fix: iteration i issues
// aload(i+1) into the ALTERNATE 8-reg buffer; the MFMA phase consumes
// the buffer filled one full iteration (~2800 cyc) earlier -> the
// 330 cyc/iter L2-latency stall R6 measured is gone. Parity-selected
// buffers are compile-time under unroll 2 (rule #20). VGPR ~105 < 128
// cap (launch_bounds 1024,4). All other scheduling identical to R6.
// ---------------------------------------------------------------------------
__global__ __launch_bounds__(1024, 4) void k_fused(
    const short* __restrict__ A2r, const unsigned short* __restrict__ xT,
    const float4* __restrict__ planw, const int4* __restrict__ plani,
    const float* __restrict__ bias, float* __restrict__ out)
{
    __shared__ short Bs[2][4][64 * 32];    // [buf][cc][px*32 + g*8]  32 KB
    const int t = threadIdx.x;
    const int wid = __builtin_amdgcn_readfirstlane(t >> 6);  // 0..15
    const int lane = t & 63;
    const int quad = lane >> 4, l16 = lane & 15;
    const int wr = wid & 7, wc = wid >> 3;   // 8 m-slices x 2 n-halves

    // XCD swizzle: 256 blocks, 8 XCDs, 32 contiguous bn per XCD.
    const int lin = blockIdx.x;
    const int bn = ((lin & 7) << 5) | (lin >> 3);

    const int n0 = bn * 64, b = n0 >> 12;
    const char* xbb = (const char*)xT + (size_t)b * HW * 512;
    const int px = t >> 4;          // 0..63: pixel this thread samples
    const int cc = (t >> 2) & 3;    // 32-ch chunk within the K=128 tap
    const int q8 = (t & 3) * 8;     // 8-ch granule within chunk
    const int n = n0 + px;

    // Wave's A-fragment base: frag f = (j*4+ss)*16 + (wr*2+mi), 512 sh each.
    const short* Aw = A2r + (size_t)(wr * 2) * 512 + lane * 8;

    f32x4 acc[2][2];
#pragma unroll
    for (int i = 0; i < 2; ++i)
#pragma unroll
        for (int j = 0; j < 2; ++j) acc[i][j] = (f32x4){0.f, 0.f, 0.f, 0.f};

    float4 pw[2];
    int4 pi[2];
    uint4 g[4];
    uint4 arA[8], arB[8];

    auto pwload = [&](int S) { pw[S & 1] = planw[(size_t)S * 16384 + n]; };
    auto piload = [&](int S) { pi[S & 1] = plani[(size_t)S * 16384 + n]; };
    auto gather = [&](int j) {
        const int cb = ((j >= 9 ? 128 : 0) + cc * 32 + q8) * 2;
        const int4 i4 = pi[j & 1];
        g[0] = *(const uint4*)(xbb + i4.x + cb);
        g[1] = *(const uint4*)(xbb + i4.y + cb);
        g[2] = *(const uint4*)(xbb + i4.z + cb);
        g[3] = *(const uint4*)(xbb + i4.w + cb);
    };
    auto aload = [&](int j, uint4 (&ar)[8]) {
#pragma unroll
        for (int ss = 0; ss < 4; ++ss)
#pragma unroll
            for (int mi = 0; mi < 2; ++mi)
                ar[ss * 2 + mi] =
                    *(const uint4*)(Aw + (size_t)(j * 4 + ss) * 8192 + mi * 512);
    };
    const int bsw = ((t & 3) ^ ((px >> 1) & 3)) * 8;  // swizzled WRITE granule
    auto packwrite = [&](int j, int buf) {
        const float4 w4 = pw[j & 1];
        float a0 = w4.x * blo(g[0].x) + w4.y * blo(g[1].x) + w4.z * blo(g[2].x) + w4.w * blo(g[3].x);
        float a1 = w4.x * bhi(g[0].x) + w4.y * bhi(g[1].x) + w4.z * bhi(g[2].x) + w4.w * bhi(g[3].x);
        float a2v = w4.x * blo(g[0].y) + w4.y * blo(g[1].y) + w4.z * blo(g[2].y) + w4.w * blo(g[3].y);
        float a3 = w4.x * bhi(g[0].y) + w4.y * bhi(g[1].y) + w4.z * bhi(g[2].y) + w4.w * bhi(g[3].y);
        float a4 = w4.x * blo(g[0].z) + w4.y * blo(g[1].z) + w4.z * blo(g[2].z) + w4.w * blo(g[3].z);
        float a5 = w4.x * bhi(g[0].z) + w4.y * bhi(g[1].z) + w4.z * bhi(g[2].z) + w4.w * bhi(g[3].z);
        float a6 = w4.x * blo(g[0].w) + w4.y * blo(g[1].w) + w4.z * blo(g[2].w) + w4.w * blo(g[3].w);
        float a7 = w4.x * bhi(g[0].w) + w4.y * bhi(g[1].w) + w4.z * bhi(g[2].w) + w4.w * bhi(g[3].w);
        uint4 o;
        o.x = cvtpk(a0, a1); o.y = cvtpk(a2v, a3);
        o.z = cvtpk(a4, a5); o.w = cvtpk(a6, a7);
        *(uint4*)&Bs[buf][cc][px * 32 + bsw] = o;
    };
    auto mfmaPhase = [&](int p, const uint4 (&ar)[8]) {
#pragma unroll
        for (int ss = 0; ss < 4; ++ss) {
            bf16x8 bfr[2];
#pragma unroll
            for (int ni = 0; ni < 2; ++ni) {
                const int row = wc * 32 + ni * 16 + l16;
                bfr[ni] = *(const bf16x8*)&Bs[p][ss][row * 32 + (quad ^ ((row >> 1) & 3)) * 8];
            }
#pragma unroll
            for (int mi = 0; mi < 2; ++mi) {
                bf16x8 af = *(const bf16x8*)&ar[ss * 2 + mi];
#pragma unroll
                for (int ni = 0; ni < 2; ++ni)
                    acc[mi][ni] = __builtin_amdgcn_mfma_f32_16x16x32_bf16(
                        af, bfr[ni], acc[mi][ni], 0, 0, 0);
            }
        }
    };

    // prologue: tap 0 packed into Bs[0]; A for tap 0 -> arA; plans for 0/1.
    pwload(0);
    piload(0);
    gather(0);
    aload(0, arA);
    packwrite(0, 0);
    pwload(1);
    piload(1);

#pragma unroll 2
    for (int i = 0; i < 18; ++i) {
        const int p = i & 1;
        __syncthreads();
        if (i + 1 < 18) aload(i + 1, p ? arA : arB);   // for NEXT iter
        if (i + 1 < 18) gather(i + 1);       // reads pi[(i+1)&1] (1 iter old)
        if (i + 2 < 18) { pwload(i + 2); piload(i + 2); }
        __builtin_amdgcn_sched_barrier(0);   // pin: all vmem issued first
        if (p) mfmaPhase(1, arB); else mfmaPhase(0, arA);   // zero-wait A
        if (i + 1 < 18) packwrite(i + 1, 1 - p);   // uses pw[(i+1)&1], g
    }

    const int m0 = wr * 32;
#pragma unroll
    for (int mi = 0; mi < 2; ++mi)
#pragma unroll
        for (int ni = 0; ni < 2; ++ni) {
            int nn = n0 + wc * 32 + ni * 16 + l16;
            int bidx = nn >> 12, hw = nn & 4095;
            float* op = out + (size_t)bidx * 256 * 4096 + hw;
#pragma unroll
            for (int r = 0; r < 4; ++r) {
                int m = m0 + mi * 16 + quad * 4 + r;
                op[(size_t)m * 4096] = acc[mi][ni][r] + bias[m];
            }
        }
}

// ---------------------------------------------------------------------------
extern "C" void kernel_launch(void* const* d_in, const int* in_sizes, int n_in,
                              void* d_out, int out_size, void* d_ws, size_t ws_size,
                              hipStream_t stream)
{
    const float* x      = (const float*)d_in[0];
    const float* w_off  = (const float*)d_in[1];
    const float* b_off  = (const float*)d_in[2];
    const float* weight = (const float*)d_in[3];
    const float* bias   = (const float*)d_in[4];
    float* out = (float*)d_out;
    char* ws = (char*)d_ws;

    // ws layout (19,300,352 B total):
    unsigned short* xT   = (unsigned short*)(ws);           //  8,388,608
    short*          a2r  = (short*)(ws + 8388608);          //  1,179,648
    short*          wTb  = (short*)(ws + 9568256);          //    294,912
    float4*         planw= (float4*)(ws + 9863168);         //  4,718,592
    int4*           plani= (int4*)(ws + 14581760);          //  4,718,592 -> 19,300,352
    // om2p (4 split-K partials) aliases d_out; fully consumed by k_plan
    // before k_fused overwrites d_out. Stream-ordered.
    float*          om2p = (float*)d_out;

    hipLaunchKernelGGL(k_xt, dim3(64, 4, 4), dim3(256), 0, stream, x, xT);
    hipLaunchKernelGGL(k_wcvt_all, dim3(2880), dim3(256), 0, stream,
                       weight, w_off, a2r, wTb);
    hipLaunchKernelGGL(k_omgemm, dim3(256, 4), dim3(256), 0, stream, wTb, xT, om2p);
    hipLaunchKernelGGL(k_plan, dim3(1152), dim3(256), 0, stream, om2p, b_off, planw, plani);
    hipLaunchKernelGGL(k_fused, dim3(256), dim3(1024), 0, stream,
                       a2r, xT, planw, plani, bias, out);
}

// Round 8
// 142.107 us; speedup vs baseline: 1.2905x; 1.2905x over previous
//
#include <hip/hip_runtime.h>
#include <cstdint>

#define HW 4096

typedef __attribute__((ext_vector_type(8))) short bf16x8;
typedef __attribute__((ext_vector_type(4))) float f32x4;

__device__ __forceinline__ short f2bf(float f) {
    union { float f; uint32_t u; } v; v.f = f;
    uint32_t u = v.u;
    uint32_t r = (u + 0x7FFFu + ((u >> 16) & 1u)) >> 16;
    return (short)(r & 0xFFFFu);
}
__device__ __forceinline__ uint32_t cvtpk(float lo, float hi) {
    uint32_t r;
    asm("v_cvt_pk_bf16_f32 %0, %1, %2" : "=v"(r) : "v"(lo), "v"(hi));
    return r;
}
__device__ __forceinline__ float blo(uint32_t u) { return __uint_as_float(u << 16); }
__device__ __forceinline__ float bhi(uint32_t u) { return __uint_as_float(u & 0xFFFF0000u); }
__device__ __forceinline__ void glds16(const void* g, void* l) {
    __builtin_amdgcn_global_load_lds(
        (const __attribute__((address_space(1))) void*)g,
        (__attribute__((address_space(3))) void*)l, 16, 0, 0);
}

// ---------------------------------------------------------------------------
// Kernel 1: transpose x[b][c][hw] (fp32) -> xT[b][hw][c] (bf16).
// ---------------------------------------------------------------------------
__global__ __launch_bounds__(256) void k_xt(
    const float* __restrict__ x, unsigned short* __restrict__ xT)
{
    __shared__ unsigned short s[64][65];
    const int t = threadIdx.x, lane = t & 63, grp = t >> 6;
    const int hw0 = blockIdx.x * 64, c0 = blockIdx.y * 64, b = blockIdx.z;
#pragma unroll
    for (int j = 0; j < 16; ++j) {
        int cc = grp * 16 + j;
        float v = x[((size_t)(b * 256 + c0 + cc)) * HW + hw0 + lane];
        s[cc][lane] = (unsigned short)f2bf(v);
    }
    __syncthreads();
#pragma unroll
    for (int j = 0; j < 16; ++j) {
        int hw2 = grp * 16 + j;
        xT[((size_t)b * HW + hw0 + hw2) * 256 + c0 + lane] = s[lane][hw2];
    }
}

// ---------------------------------------------------------------------------
// Kernel 2 (merged): both weight conversions in one launch.
// a2r: FRAGMENT-CONTIGUOUS layout for k_fused's direct-from-L2 A-loads.
//   frag id f = (j*4 + ss)*16 + rg   (j = dg*9+tap 0..17, ss 0..3, rg 0..15)
//   a2r[f*512 + lane*8 + e] = w[o = rg*16 + (lane&15)]
//                              [k-chunk cch = ss*32 + (lane>>4)*8 + e]
// ---------------------------------------------------------------------------
__global__ __launch_bounds__(256) void k_wcvt_all(
    const float* __restrict__ weight, const float* __restrict__ w_off,
    short* __restrict__ a2r, short* __restrict__ wTb)
{
    int e = blockIdx.x * 256 + threadIdx.x;     // 737280 total
    if (e < 589824) {
        int el = e & 7;
        int lane = (e >> 3) & 63;
        int rg = (e >> 9) & 15;
        int ss = (e >> 13) & 3;
        int j = e >> 15;                        // 0..17
        int o = rg * 16 + (lane & 15);
        int cch = ss * 32 + (lane >> 4) * 8 + el;
        int dg = j / 9, tap = j - dg * 9;
        a2r[e] = f2bf(weight[o * 2304 + (dg * 128 + cch) * 9 + tap]);
    } else {
        int e2 = e - 589824;
        int o = e2 / 2304, r = e2 - o * 2304;
        int tap = r >> 8, c = r & 255;
        wTb[e2] = (o < 54) ? f2bf(w_off[(o * 256 + c) * 9 + tap]) : (short)0;
    }
}

// ---------------------------------------------------------------------------
// Kernel 3: offset conv as MFMA GEMM, split-K x4, software-pipelined.
// ---------------------------------------------------------------------------
__global__ __launch_bounds__(256, 4) void k_omgemm(
    const short* __restrict__ wTb, const unsigned short* __restrict__ xT,
    float* __restrict__ om2p)
{
    __shared__ short As[2][64 * 32];
    __shared__ short Bs[2][64 * 32];
    const int t = threadIdx.x;
    const int wid = __builtin_amdgcn_readfirstlane(t >> 6);
    const int lane = t & 63, quad = lane >> 4, l16 = lane & 15;
    const int n0 = blockIdx.x * 64, b = n0 >> 12;
    const int ks = blockIdx.y;          // 0..3 -> chunks ks*18 .. ks*18+17
    const int nr = t >> 2;
    const int ksh = (t & 3) * 8;
    const int px = (n0 + nr) & 4095, h = px >> 6, w = px & 63;
    const unsigned short* xb = xT + (size_t)b * HW * 256;
    const int cbase = ks * 18;

    auto loadB = [&](int c) -> uint4 {
        int tap = c >> 3, c0 = (c & 7) * 32;
        int hh = h + tap / 3 - 1, ww = w + tap % 3 - 1;
        uint4 bv = {0u, 0u, 0u, 0u};
        if (hh >= 0 && hh < 64 && ww >= 0 && ww < 64)
            bv = *(const uint4*)(xb + (size_t)(hh * 64 + ww) * 256 + c0 + ksh);
        return bv;
    };

    f32x4 acc[4];
#pragma unroll
    for (int i = 0; i < 4; ++i) acc[i] = (f32x4){0.f, 0.f, 0.f, 0.f};

    uint4 bv[2];
    bv[0] = loadB(cbase);
    glds16(wTb + (size_t)nr * 2304 + cbase * 32 + ksh, &As[0][t * 8]);
    *(uint4*)&Bs[0][t * 8] = bv[0];
    bv[1] = loadB(cbase + 1);

#pragma unroll 2
    for (int i = 0; i < 18; ++i) {
        const int p = i & 1;
        __syncthreads();
        if (i < 17) {
            glds16(wTb + (size_t)nr * 2304 + (cbase + i + 1) * 32 + ksh,
                   &As[1 - p][t * 8]);
            *(uint4*)&Bs[1 - p][t * 8] = bv[(i + 1) & 1];
        }
        if (i + 2 < 18) bv[i & 1] = loadB(cbase + i + 2);
        bf16x8 bf = *(const bf16x8*)&Bs[p][(wid * 16 + l16) * 32 + quad * 8];
#pragma unroll
        for (int mi = 0; mi < 4; ++mi) {
            bf16x8 af = *(const bf16x8*)&As[p][(mi * 16 + l16) * 32 + quad * 8];
            acc[mi] = __builtin_amdgcn_mfma_f32_16x16x32_bf16(af, bf, acc[mi], 0, 0, 0);
        }
    }
    const int n = n0 + wid * 16 + l16;
#pragma unroll
    for (int mi = 0; mi < 4; ++mi)
#pragma unroll
        for (int i = 0; i < 4; ++i)
            om2p[(size_t)(ks * 64 + mi * 16 + quad * 4 + i) * 16384 + n] = acc[mi][i];
}

// ---------------------------------------------------------------------------
// Kernel 5: sampling plan (sums 4 split-K partials).
// ---------------------------------------------------------------------------
__global__ __launch_bounds__(256) void k_plan(
    const float* __restrict__ om2p, const float* __restrict__ b_off,
    float4* __restrict__ planw, int4* __restrict__ plani)
{
    int e = blockIdx.x * 256 + threadIdx.x;      // 294912
    int n = e & 16383, s = e >> 14;
    int dg = s >= 9 ? 1 : 0, tap = s - dg * 9;
    int h = (n >> 6) & 63, w = n & 63;
    int cdy = dg * 18 + tap, cdx = cdy + 9, cms = 36 + dg * 9 + tap;
    float dy = b_off[cdy], dx = b_off[cdx], ms = b_off[cms];
#pragma unroll
    for (int cs = 0; cs < 4; ++cs) {
        const float* p = om2p + (size_t)cs * 64 * 16384;
        dy += p[(size_t)cdy * 16384 + n];
        dx += p[(size_t)cdx * 16384 + n];
        ms += p[(size_t)cms * 16384 + n];
    }
    ms = 1.f / (1.f + __expf(-ms));
    float py = dy + (float)(h + tap / 3 - 1);
    float qx = dx + (float)(w + tap % 3 - 1);
    float y0f = floorf(py), x0f = floorf(qx);
    float wy1 = py - y0f, wx1 = qx - x0f;
    float wy0 = 1.f - wy1, wx0 = 1.f - wx1;
    int y0 = (int)y0f, x0 = (int)x0f;
    int y1 = y0 + 1, x1 = x0 + 1;
    bool vy0 = (y0 >= 0) & (y0 < 64), vy1 = (y1 >= 0) & (y1 < 64);
    bool vx0 = (x0 >= 0) & (x0 < 64), vx1 = (x1 >= 0) & (x1 < 64);
    int cy0 = min(max(y0, 0), 63), cy1 = min(max(y1, 0), 63);
    int cx0 = min(max(x0, 0), 63), cx1 = min(max(x1, 0), 63);
    float4 wv;
    wv.x = (vy0 && vx0) ? wy0 * wx0 * ms : 0.f;
    wv.y = (vy0 && vx1) ? wy0 * wx1 * ms : 0.f;
    wv.z = (vy1 && vx0) ? wy1 * wx0 * ms : 0.f;
    wv.w = (vy1 && vx1) ? wy1 * wx1 * ms : 0.f;
    int4 iv = make_int4((cy0 * 64 + cx0) << 9, (cy0 * 64 + cx1) << 9,
                        (cy1 * 64 + cx0) << 9, (cy1 * 64 + cx1) << 9);
    planw[e] = wv;
    plani[e] = iv;
}

// ---------------------------------------------------------------------------
// Kernel 6: FUSED sampling + GEMM — A direct from L2 + 2 BLOCKS/CU via
// PIXEL-SPLIT. 512 thr (8 waves), tile 32px x 256m, grid 512 = 2/CU.
// Splitting by PIXELS (not m) keeps gather+pack done once per pixel (the
// R2 win preserved); A-loads from L2 are duplicated across the two
// blocks but cost L2 BW (ample), not VALU. LDS = Bs only, 16 KB/block ->
// 2 blocks co-resident trivially (R3's 80KB failure solved by R6's
// A-direct). Two independent barrier domains/CU: block A's drains and
// L2 latencies are covered by block B's waves. A-regs single-buffered
// (R7 spill lesson: no runtime-selected array refs); aload(i+1) issued
// after the MFMA phase (packwrite + barrier + other-block cover).
// vmem per iter: aload(8) + gather(4) + pw/pi(2). Plain __syncthreads.
// ---------------------------------------------------------------------------
__global__ __launch_bounds__(512, 4) void k_fused(
    const short* __restrict__ A2r, const unsigned short* __restrict__ xT,
    const float4* __restrict__ planw, const int4* __restrict__ plani,
    const float* __restrict__ bias, float* __restrict__ out)
{
    __shared__ short Bs[2][4][32 * 32];    // [buf][cc][px*32 + g*8]  16 KB
    const int t = threadIdx.x;
    const int wid = __builtin_amdgcn_readfirstlane(t >> 6);  // 0..7
    const int lane = t & 63;
    const int quad = lane >> 4, l16 = lane & 15;
    const int wr = wid;                     // 8 m-slices of 32

    // XCD swizzle: 512 blocks, 8 XCDs, 64 contiguous bn per XCD.
    const int lin = blockIdx.x;
    const int bn = ((lin & 7) << 6) | (lin >> 3);

    const int n0 = bn * 32, b = n0 >> 12;
    const char* xbb = (const char*)xT + (size_t)b * HW * 512;
    const int px = t >> 4;          // 0..31: pixel this thread samples
    const int cc = (t >> 2) & 3;    // 32-ch chunk within the K=128 tap
    const int q8 = (t & 3) * 8;     // 8-ch granule within chunk
    const int n = n0 + px;

    // Wave's A-fragment base: frag f = (j*4+ss)*16 + (wr*2+mi), 512 sh each.
    const short* Aw = A2r + (size_t)(wr * 2) * 512 + lane * 8;

    f32x4 acc[2][2];
#pragma unroll
    for (int i = 0; i < 2; ++i)
#pragma unroll
        for (int j = 0; j < 2; ++j) acc[i][j] = (f32x4){0.f, 0.f, 0.f, 0.f};

    float4 pw[2];
    int4 pi[2];
    uint4 g[4];
    uint4 ar[8];

    auto pwload = [&](int S) { pw[S & 1] = planw[(size_t)S * 16384 + n]; };
    auto piload = [&](int S) { pi[S & 1] = plani[(size_t)S * 16384 + n]; };
    auto gather = [&](int j) {
        const int cb = ((j >= 9 ? 128 : 0) + cc * 32 + q8) * 2;
        const int4 i4 = pi[j & 1];
        g[0] = *(const uint4*)(xbb + i4.x + cb);
        g[1] = *(const uint4*)(xbb + i4.y + cb);
        g[2] = *(const uint4*)(xbb + i4.z + cb);
        g[3] = *(const uint4*)(xbb + i4.w + cb);
    };
    auto aload = [&](int j) {
#pragma unroll
        for (int ss = 0; ss < 4; ++ss)
#pragma unroll
            for (int mi = 0; mi < 2; ++mi)
                ar[ss * 2 + mi] =
                    *(const uint4*)(Aw + (size_t)(j * 4 + ss) * 8192 + mi * 512);
    };
    const int bsw = ((t & 3) ^ ((px >> 1) & 3)) * 8;  // swizzled WRITE granule
    auto packwrite = [&](int j, int buf) {
        const float4 w4 = pw[j & 1];
        float a0 = w4.x * blo(g[0].x) + w4.y * blo(g[1].x) + w4.z * blo(g[2].x) + w4.w * blo(g[3].x);
        float a1 = w4.x * bhi(g[0].x) + w4.y * bhi(g[1].x) + w4.z * bhi(g[2].x) + w4.w * bhi(g[3].x);
        float a2v = w4.x * blo(g[0].y) + w4.y * blo(g[1].y) + w4.z * blo(g[2].y) + w4.w * blo(g[3].y);
        float a3 = w4.x * bhi(g[0].y) + w4.y * bhi(g[1].y) + w4.z * bhi(g[2].y) + w4.w * bhi(g[3].y);
        float a4 = w4.x * blo(g[0].z) + w4.y * blo(g[1].z) + w4.z * blo(g[2].z) + w4.w * blo(g[3].z);
        float a5 = w4.x * bhi(g[0].z) + w4.y * bhi(g[1].z) + w4.z * bhi(g[2].z) + w4.w * bhi(g[3].z);
        float a6 = w4.x * blo(g[0].w) + w4.y * blo(g[1].w) + w4.z * blo(g[2].w) + w4.w * blo(g[3].w);
        float a7 = w4.x * bhi(g[0].w) + w4.y * bhi(g[1].w) + w4.z * bhi(g[2].w) + w4.w * bhi(g[3].w);
        uint4 o;
        o.x = cvtpk(a0, a1); o.y = cvtpk(a2v, a3);
        o.z = cvtpk(a4, a5); o.w = cvtpk(a6, a7);
        *(uint4*)&Bs[buf][cc][px * 32 + bsw] = o;
    };
    auto mfmaPhase = [&](int p) {
#pragma unroll
        for (int ss = 0; ss < 4; ++ss) {
            bf16x8 bfr[2];
#pragma unroll
            for (int ni = 0; ni < 2; ++ni) {
                const int row = ni * 16 + l16;
                bfr[ni] = *(const bf16x8*)&Bs[p][ss][row * 32 + (quad ^ ((row >> 1) & 3)) * 8];
            }
#pragma unroll
            for (int mi = 0; mi < 2; ++mi) {
                bf16x8 af = *(const bf16x8*)&ar[ss * 2 + mi];
#pragma unroll
                for (int ni = 0; ni < 2; ++ni)
                    acc[mi][ni] = __builtin_amdgcn_mfma_f32_16x16x32_bf16(
                        af, bfr[ni], acc[mi][ni], 0, 0, 0);
            }
        }
    };

    // prologue: tap 0 packed into Bs[0]; A for tap 0 in ar; plans for 0/1.
    pwload(0);
    piload(0);
    gather(0);
    aload(0);
    packwrite(0, 0);
    pwload(1);
    piload(1);

#pragma unroll 2
    for (int i = 0; i < 18; ++i) {
        const int p = i & 1;
        __syncthreads();
        if (i + 1 < 18) gather(i + 1);       // reads pi[(i+1)&1] (1 iter old)
        if (i + 2 < 18) { pwload(i + 2); piload(i + 2); }
        __builtin_amdgcn_sched_barrier(0);   // pin: gathers/plans issued first
        mfmaPhase(p);                        // consumes ar (tap i), Bs[p]
        if (i + 1 < 18) aload(i + 1);        // overwrite ar AFTER MFMA reads
        if (i + 1 < 18) packwrite(i + 1, 1 - p);   // uses pw[(i+1)&1], g
    }

    const int m0 = wr * 32;
#pragma unroll
    for (int mi = 0; mi < 2; ++mi)
#pragma unroll
        for (int ni = 0; ni < 2; ++ni) {
            int nn = n0 + ni * 16 + l16;
            int bidx = nn >> 12, hw = nn & 4095;
            float* op = out + (size_t)bidx * 256 * 4096 + hw;
#pragma unroll
            for (int r = 0; r < 4; ++r) {
                int m = m0 + mi * 16 + quad * 4 + r;
                op[(size_t)m * 4096] = acc[mi][ni][r] + bias[m];
            }
        }
}

// ---------------------------------------------------------------------------
extern "C" void kernel_launch(void* const* d_in, const int* in_sizes, int n_in,
                              void* d_out, int out_size, void* d_ws, size_t ws_size,
                              hipStream_t stream)
{
    const float* x      = (const float*)d_in[0];
    const float* w_off  = (const float*)d_in[1];
    const float* b_off  = (const float*)d_in[2];
    const float* weight = (const float*)d_in[3];
    const float* bias   = (const float*)d_in[4];
    float* out = (float*)d_out;
    char* ws = (char*)d_ws;

    // ws layout (19,300,352 B total):
    unsigned short* xT   = (unsigned short*)(ws);           //  8,388,608
    short*          a2r  = (short*)(ws + 8388608);          //  1,179,648
    short*          wTb  = (short*)(ws + 9568256);          //    294,912
    float4*         planw= (float4*)(ws + 9863168);         //  4,718,592
    int4*           plani= (int4*)(ws + 14581760);          //  4,718,592 -> 19,300,352
    // om2p (4 split-K partials) aliases d_out; fully consumed by k_plan
    // before k_fused overwrites d_out. Stream-ordered.
    float*          om2p = (float*)d_out;

    hipLaunchKernelGGL(k_xt, dim3(64, 4, 4), dim3(256), 0, stream, x, xT);
    hipLaunchKernelGGL(k_wcvt_all, dim3(2880), dim3(256), 0, stream,
                       weight, w_off, a2r, wTb);
    hipLaunchKernelGGL(k_omgemm, dim3(256, 4), dim3(256), 0, stream, wTb, xT, om2p);
    hipLaunchKernelGGL(k_plan, dim3(1152), dim3(256), 0, stream, om2p, b_off, planw, plani);
    hipLaunchKernelGGL(k_fused, dim3(512), dim3(512), 0, stream,
                       a2r, xT, planw, plani, bias, out);
}

// Round 9
// 129.187 us; speedup vs baseline: 1.4196x; 1.1000x over previous
//
#include <hip/hip_runtime.h>
#include <cstdint>

#define HW 4096

typedef __attribute__((ext_vector_type(8))) short bf16x8;
typedef __attribute__((ext_vector_type(4))) float f32x4;

__device__ __forceinline__ short f2bf(float f) {
    union { float f; uint32_t u; } v; v.f = f;
    uint32_t u = v.u;
    uint32_t r = (u + 0x7FFFu + ((u >> 16) & 1u)) >> 16;
    return (short)(r & 0xFFFFu);
}
__device__ __forceinline__ uint32_t cvtpk(float lo, float hi) {
    uint32_t r;
    asm("v_cvt_pk_bf16_f32 %0, %1, %2" : "=v"(r) : "v"(lo), "v"(hi));
    return r;
}
__device__ __forceinline__ float blo(uint32_t u) { return __uint_as_float(u << 16); }
__device__ __forceinline__ float bhi(uint32_t u) { return __uint_as_float(u & 0xFFFF0000u); }
__device__ __forceinline__ void glds16(const void* g, void* l) {
    __builtin_amdgcn_global_load_lds(
        (const __attribute__((address_space(1))) void*)g,
        (__attribute__((address_space(3))) void*)l, 16, 0, 0);
}

// ---------------------------------------------------------------------------
// Kernel 1 (merged k_xt + k_wcvt_all): one launch for all preprocessing.
// blocks 0..1023  : transpose x[b][c][hw] fp32 -> xT[b][hw][c] bf16
// blocks 1024..   : weight conversions (a2r fragment-contiguous + wTb)
// a2r layout: frag f = (j*4+ss)*16 + rg; a2r[f*512 + lane*8 + e] =
//   w[o = rg*16 + (lane&15)][k-chunk cch = ss*32 + (lane>>4)*8 + e]
// ---------------------------------------------------------------------------
__global__ __launch_bounds__(256) void k_pre(
    const float* __restrict__ x, const float* __restrict__ weight,
    const float* __restrict__ w_off, unsigned short* __restrict__ xT,
    short* __restrict__ a2r, short* __restrict__ wTb)
{
    const int bid = blockIdx.x;
    if (bid < 1024) {
        __shared__ unsigned short s[64][65];
        const int t = threadIdx.x, lane = t & 63, grp = t >> 6;
        const int hw0 = (bid & 63) * 64, c0 = ((bid >> 6) & 3) * 64, b = bid >> 8;
#pragma unroll
        for (int j = 0; j < 16; ++j) {
            int cc = grp * 16 + j;
            float v = x[((size_t)(b * 256 + c0 + cc)) * HW + hw0 + lane];
            s[cc][lane] = (unsigned short)f2bf(v);
        }
        __syncthreads();
#pragma unroll
        for (int j = 0; j < 16; ++j) {
            int hw2 = grp * 16 + j;
            xT[((size_t)b * HW + hw0 + hw2) * 256 + c0 + lane] = s[lane][hw2];
        }
    } else {
        int e = (bid - 1024) * 256 + threadIdx.x;   // 0..737279
        if (e < 589824) {
            int el = e & 7;
            int lane = (e >> 3) & 63;
            int rg = (e >> 9) & 15;
            int ss = (e >> 13) & 3;
            int j = e >> 15;                        // 0..17
            int o = rg * 16 + (lane & 15);
            int cch = ss * 32 + (lane >> 4) * 8 + el;
            int dg = j / 9, tap = j - dg * 9;
            a2r[e] = f2bf(weight[o * 2304 + (dg * 128 + cch) * 9 + tap]);
        } else {
            int e2 = e - 589824;
            int o = e2 / 2304, r = e2 - o * 2304;
            int tap = r >> 8, c = r & 255;
            wTb[e2] = (o < 54) ? f2bf(w_off[(o * 256 + c) * 9 + tap]) : (short)0;
        }
    }
}

// ---------------------------------------------------------------------------
// Kernel 2: offset conv as MFMA GEMM, split-K x4, software-pipelined.
// om2p now lives in ws (no longer aliases d_out).
// ---------------------------------------------------------------------------
__global__ __launch_bounds__(256, 4) void k_omgemm(
    const short* __restrict__ wTb, const unsigned short* __restrict__ xT,
    float* __restrict__ om2p)
{
    __shared__ short As[2][64 * 32];
    __shared__ short Bs[2][64 * 32];
    const int t = threadIdx.x;
    const int wid = __builtin_amdgcn_readfirstlane(t >> 6);
    const int lane = t & 63, quad = lane >> 4, l16 = lane & 15;
    const int n0 = blockIdx.x * 64, b = n0 >> 12;
    const int ks = blockIdx.y;          // 0..3 -> chunks ks*18 .. ks*18+17
    const int nr = t >> 2;
    const int ksh = (t & 3) * 8;
    const int px = (n0 + nr) & 4095, h = px >> 6, w = px & 63;
    const unsigned short* xb = xT + (size_t)b * HW * 256;
    const int cbase = ks * 18;

    auto loadB = [&](int c) -> uint4 {
        int tap = c >> 3, c0 = (c & 7) * 32;
        int hh = h + tap / 3 - 1, ww = w + tap % 3 - 1;
        uint4 bv = {0u, 0u, 0u, 0u};
        if (hh >= 0 && hh < 64 && ww >= 0 && ww < 64)
            bv = *(const uint4*)(xb + (size_t)(hh * 64 + ww) * 256 + c0 + ksh);
        return bv;
    };

    f32x4 acc[4];
#pragma unroll
    for (int i = 0; i < 4; ++i) acc[i] = (f32x4){0.f, 0.f, 0.f, 0.f};

    uint4 bv[2];
    bv[0] = loadB(cbase);
    glds16(wTb + (size_t)nr * 2304 + cbase * 32 + ksh, &As[0][t * 8]);
    *(uint4*)&Bs[0][t * 8] = bv[0];
    bv[1] = loadB(cbase + 1);

#pragma unroll 2
    for (int i = 0; i < 18; ++i) {
        const int p = i & 1;
        __syncthreads();
        if (i < 17) {
            glds16(wTb + (size_t)nr * 2304 + (cbase + i + 1) * 32 + ksh,
                   &As[1 - p][t * 8]);
            *(uint4*)&Bs[1 - p][t * 8] = bv[(i + 1) & 1];
        }
        if (i + 2 < 18) bv[i & 1] = loadB(cbase + i + 2);
        bf16x8 bf = *(const bf16x8*)&Bs[p][(wid * 16 + l16) * 32 + quad * 8];
#pragma unroll
        for (int mi = 0; mi < 4; ++mi) {
            bf16x8 af = *(const bf16x8*)&As[p][(mi * 16 + l16) * 32 + quad * 8];
            acc[mi] = __builtin_amdgcn_mfma_f32_16x16x32_bf16(af, bf, acc[mi], 0, 0, 0);
        }
    }
    const int n = n0 + wid * 16 + l16;
#pragma unroll
    for (int mi = 0; mi < 4; ++mi)
#pragma unroll
        for (int i = 0; i < 4; ++i)
            om2p[(size_t)(ks * 64 + mi * 16 + quad * 4 + i) * 16384 + n] = acc[mi][i];
}

// ---------------------------------------------------------------------------
// Kernel 3: FUSED plan + sampling + GEMM. R8 structure (512 thr / 8 waves,
// 32px x 256m, A direct from L2, 2 blocks/CU) + IN-BLOCK PLAN PROLOGUE:
// the pixel-split makes each block's 32-px plan disjoint, so the block
// computes its own 18 taps x 32 px plan from om2p (27 KB coalesced reads,
// sigmoid/bilinear math identical to old k_plan) into LDS (18 KB), and
// the main loop reads pw/pi from LDS. Deletes the k_plan kernel, its
// launch gap, and the 19 MB planw/plani HBM round-trip. om2p moved into
// ws so k_fused may read it while writing d_out (no aliasing race).
// LDS: Bs 16 KB + plan 18 KB = 34.8 KB -> 2 blocks/CU still fits.
// ---------------------------------------------------------------------------
__global__ __launch_bounds__(512, 4) void k_fused(
    const short* __restrict__ A2r, const unsigned short* __restrict__ xT,
    const float* __restrict__ om2p, const float* __restrict__ b_off,
    const float* __restrict__ bias, float* __restrict__ out)
{
    __shared__ short Bs[2][4][32 * 32];    // [buf][cc][px*32 + g*8]  16 KB
    __shared__ float4 PlnW[18][32];        // 9 KB
    __shared__ int4   PlnI[18][32];        // 9 KB
    const int t = threadIdx.x;
    const int wid = __builtin_amdgcn_readfirstlane(t >> 6);  // 0..7
    const int lane = t & 63;
    const int quad = lane >> 4, l16 = lane & 15;
    const int wr = wid;                     // 8 m-slices of 32

    // XCD swizzle: 512 blocks, 8 XCDs, 64 contiguous bn per XCD.
    const int lin = blockIdx.x;
    const int bn = ((lin & 7) << 6) | (lin >> 3);

    const int n0 = bn * 32, b = n0 >> 12;
    const char* xbb = (const char*)xT + (size_t)b * HW * 512;
    const int px = t >> 4;          // 0..31: pixel this thread samples
    const int cc = (t >> 2) & 3;    // 32-ch chunk within the K=128 tap
    const int q8 = (t & 3) * 8;     // 8-ch granule within chunk

    // ---- plan prologue: wave w computes taps s = w, w+8, w+16 ----
    for (int s = wid; s < 18; s += 8) {
        if (lane < 32) {
            const int nn = n0 + lane;
            const int dg = s >= 9 ? 1 : 0, tap = s - dg * 9;
            const int hh = (nn >> 6) & 63, ww2 = nn & 63;
            const int cdy = dg * 18 + tap, cdx = cdy + 9, cms = 36 + dg * 9 + tap;
            float dy = b_off[cdy], dx = b_off[cdx], ms = b_off[cms];
#pragma unroll
            for (int cs2 = 0; cs2 < 4; ++cs2) {
                const float* pp = om2p + (size_t)cs2 * 64 * 16384;
                dy += pp[(size_t)cdy * 16384 + nn];
                dx += pp[(size_t)cdx * 16384 + nn];
                ms += pp[(size_t)cms * 16384 + nn];
            }
            ms = 1.f / (1.f + __expf(-ms));
            float py = dy + (float)(hh + tap / 3 - 1);
            float qx = dx + (float)(ww2 + tap % 3 - 1);
            float y0f = floorf(py), x0f = floorf(qx);
            float wy1 = py - y0f, wx1 = qx - x0f;
            float wy0 = 1.f - wy1, wx0 = 1.f - wx1;
            int y0 = (int)y0f, x0 = (int)x0f;
            int y1 = y0 + 1, x1 = x0 + 1;
            bool vy0 = (y0 >= 0) & (y0 < 64), vy1 = (y1 >= 0) & (y1 < 64);
            bool vx0 = (x0 >= 0) & (x0 < 64), vx1 = (x1 >= 0) & (x1 < 64);
            int cy0 = min(max(y0, 0), 63), cy1 = min(max(y1, 0), 63);
            int cx0 = min(max(x0, 0), 63), cx1 = min(max(x1, 0), 63);
            float4 wv;
            wv.x = (vy0 && vx0) ? wy0 * wx0 * ms : 0.f;
            wv.y = (vy0 && vx1) ? wy0 * wx1 * ms : 0.f;
            wv.z = (vy1 && vx0) ? wy1 * wx0 * ms : 0.f;
            wv.w = (vy1 && vx1) ? wy1 * wx1 * ms : 0.f;
            int4 iv = make_int4((cy0 * 64 + cx0) << 9, (cy0 * 64 + cx1) << 9,
                                (cy1 * 64 + cx0) << 9, (cy1 * 64 + cx1) << 9);
            PlnW[s][lane] = wv;
            PlnI[s][lane] = iv;
        }
    }
    __syncthreads();

    // Wave's A-fragment base: frag f = (j*4+ss)*16 + (wr*2+mi), 512 sh each.
    const short* Aw = A2r + (size_t)(wr * 2) * 512 + lane * 8;

    f32x4 acc[2][2];
#pragma unroll
    for (int i = 0; i < 2; ++i)
#pragma unroll
        for (int j = 0; j < 2; ++j) acc[i][j] = (f32x4){0.f, 0.f, 0.f, 0.f};

    float4 pw[2];
    int4 pi[2];
    uint4 g[4];
    uint4 ar[8];

    auto pwload = [&](int S) { pw[S & 1] = PlnW[S][px]; };
    auto piload = [&](int S) { pi[S & 1] = PlnI[S][px]; };
    auto gather = [&](int j) {
        const int cb = ((j >= 9 ? 128 : 0) + cc * 32 + q8) * 2;
        const int4 i4 = pi[j & 1];
        g[0] = *(const uint4*)(xbb + i4.x + cb);
        g[1] = *(const uint4*)(xbb + i4.y + cb);
        g[2] = *(const uint4*)(xbb + i4.z + cb);
        g[3] = *(const uint4*)(xbb + i4.w + cb);
    };
    auto aload = [&](int j) {
#pragma unroll
        for (int ss = 0; ss < 4; ++ss)
#pragma unroll
            for (int mi = 0; mi < 2; ++mi)
                ar[ss * 2 + mi] =
                    *(const uint4*)(Aw + (size_t)(j * 4 + ss) * 8192 + mi * 512);
    };
    const int bsw = ((t & 3) ^ ((px >> 1) & 3)) * 8;  // swizzled WRITE granule
    auto packwrite = [&](int j, int buf) {
        const float4 w4 = pw[j & 1];
        float a0 = w4.x * blo(g[0].x) + w4.y * blo(g[1].x) + w4.z * blo(g[2].x) + w4.w * blo(g[3].x);
        float a1 = w4.x * bhi(g[0].x) + w4.y * bhi(g[1].x) + w4.z * bhi(g[2].x) + w4.w * bhi(g[3].x);
        float a2v = w4.x * blo(g[0].y) + w4.y * blo(g[1].y) + w4.z * blo(g[2].y) + w4.w * blo(g[3].y);
        float a3 = w4.x * bhi(g[0].y) + w4.y * bhi(g[1].y) + w4.z * bhi(g[2].y) + w4.w * bhi(g[3].y);
        float a4 = w4.x * blo(g[0].z) + w4.y * blo(g[1].z) + w4.z * blo(g[2].z) + w4.w * blo(g[3].z);
        float a5 = w4.x * bhi(g[0].z) + w4.y * bhi(g[1].z) + w4.z * bhi(g[2].z) + w4.w * bhi(g[3].z);
        float a6 = w4.x * blo(g[0].w) + w4.y * blo(g[1].w) + w4.z * blo(g[2].w) + w4.w * blo(g[3].w);
        float a7 = w4.x * bhi(g[0].w) + w4.y * bhi(g[1].w) + w4.z * bhi(g[2].w) + w4.w * bhi(g[3].w);
        uint4 o;
        o.x = cvtpk(a0, a1); o.y = cvtpk(a2v, a3);
        o.z = cvtpk(a4, a5); o.w = cvtpk(a6, a7);
        *(uint4*)&Bs[buf][cc][px * 32 + bsw] = o;
    };
    auto mfmaPhase = [&](int p) {
#pragma unroll
        for (int ss = 0; ss < 4; ++ss) {
            bf16x8 bfr[2];
#pragma unroll
            for (int ni = 0; ni < 2; ++ni) {
                const int row = ni * 16 + l16;
                bfr[ni] = *(const bf16x8*)&Bs[p][ss][row * 32 + (quad ^ ((row >> 1) & 3)) * 8];
            }
#pragma unroll
            for (int mi = 0; mi < 2; ++mi) {
                bf16x8 af = *(const bf16x8*)&ar[ss * 2 + mi];
#pragma unroll
                for (int ni = 0; ni < 2; ++ni)
                    acc[mi][ni] = __builtin_amdgcn_mfma_f32_16x16x32_bf16(
                        af, bfr[ni], acc[mi][ni], 0, 0, 0);
            }
        }
    };

    // prologue: tap 0 packed into Bs[0]; A for tap 0 in ar; plans for 0/1.
    pwload(0);
    piload(0);
    gather(0);
    aload(0);
    packwrite(0, 0);
    pwload(1);
    piload(1);

#pragma unroll 2
    for (int i = 0; i < 18; ++i) {
        const int p = i & 1;
        __syncthreads();
        if (i + 1 < 18) gather(i + 1);       // reads pi[(i+1)&1] (1 iter old)
        if (i + 2 < 18) { pwload(i + 2); piload(i + 2); }
        __builtin_amdgcn_sched_barrier(0);   // pin: gathers/plans issued first
        mfmaPhase(p);                        // consumes ar (tap i), Bs[p]
        if (i + 1 < 18) aload(i + 1);        // overwrite ar AFTER MFMA reads
        if (i + 1 < 18) packwrite(i + 1, 1 - p);   // uses pw[(i+1)&1], g
    }

    const int m0 = wr * 32;
#pragma unroll
    for (int mi = 0; mi < 2; ++mi)
#pragma unroll
        for (int ni = 0; ni < 2; ++ni) {
            int nn = n0 + ni * 16 + l16;
            int bidx = nn >> 12, hw = nn & 4095;
            float* op = out + (size_t)bidx * 256 * 4096 + hw;
#pragma unroll
            for (int r = 0; r < 4; ++r) {
                int m = m0 + mi * 16 + quad * 4 + r;
                op[(size_t)m * 4096] = acc[mi][ni][r] + bias[m];
            }
        }
}

// ---------------------------------------------------------------------------
extern "C" void kernel_launch(void* const* d_in, const int* in_sizes, int n_in,
                              void* d_out, int out_size, void* d_ws, size_t ws_size,
                              hipStream_t stream)
{
    const float* x      = (const float*)d_in[0];
    const float* w_off  = (const float*)d_in[1];
    const float* b_off  = (const float*)d_in[2];
    const float* weight = (const float*)d_in[3];
    const float* bias   = (const float*)d_in[4];
    float* out = (float*)d_out;
    char* ws = (char*)d_ws;

    // ws layout (26,640,384 B used; harness fill evidence: ws ~= 256 MB):
    unsigned short* xT   = (unsigned short*)(ws);           //  8,388,608
    short*          a2r  = (short*)(ws + 8388608);          //  1,179,648
    short*          wTb  = (short*)(ws + 9568256);          //    294,912
    float*          om2p = (float*)(ws + 9863168);          // 16,777,216 -> 26,640,384
    // om2p no longer aliases d_out (k_fused reads it while writing out).

    hipLaunchKernelGGL(k_pre, dim3(3904), dim3(256), 0, stream,
                       x, weight, w_off, xT, a2r, wTb);
    hipLaunchKernelGGL(k_omgemm, dim3(256, 4), dim3(256), 0, stream, wTb, xT, om2p);
    hipLaunchKernelGGL(k_fused, dim3(512), dim3(512), 0, stream,
                       a2r, xT, om2p, b_off, bias, out);
}

// Round 10
// 124.918 us; speedup vs baseline: 1.4681x; 1.0342x over previous
//
#include <hip/hip_runtime.h>
#include <cstdint>

#define HW 4096

typedef __attribute__((ext_vector_type(8))) short bf16x8;
typedef __attribute__((ext_vector_type(4))) float f32x4;

__device__ __forceinline__ short f2bf(float f) {
    union { float f; uint32_t u; } v; v.f = f;
    uint32_t u = v.u;
    uint32_t r = (u + 0x7FFFu + ((u >> 16) & 1u)) >> 16;
    return (short)(r & 0xFFFFu);
}
__device__ __forceinline__ uint32_t cvtpk(float lo, float hi) {
    uint32_t r;
    asm("v_cvt_pk_bf16_f32 %0, %1, %2" : "=v"(r) : "v"(lo), "v"(hi));
    return r;
}
__device__ __forceinline__ float blo(uint32_t u) { return __uint_as_float(u << 16); }
__device__ __forceinline__ float bhi(uint32_t u) { return __uint_as_float(u & 0xFFFF0000u); }

// ---------------------------------------------------------------------------
// Kernel 1 (k_pre): all preprocessing in one launch.
// blocks 0..1023  : transpose x[b][c][hw] fp32 -> xT[b][hw][c] bf16
// blocks 1024..   : weight conversions:
//   a2r  (deformable GEMM A, fragment-contiguous):
//     frag f = (j*4+ss)*16 + rg; a2r[f*512 + lane*8 + e] =
//       w[o = rg*16 + (lane&15)][cch = ss*32 + (lane>>4)*8 + e]  (per j tap)
//   wTb2 (offset-conv A, fragment-contiguous for the in-block om GEMM):
//     wTb2[c*2048 + mi2*512 + lane*8 + e] = wom[o = mi2*16 + (lane&15)]
//       [k = c*32 + (lane>>4)*8 + e]   (k: tap = k>>8, ch = k&255; o<54 else 0)
// ---------------------------------------------------------------------------
__global__ __launch_bounds__(256) void k_pre(
    const float* __restrict__ x, const float* __restrict__ weight,
    const float* __restrict__ w_off, unsigned short* __restrict__ xT,
    short* __restrict__ a2r, short* __restrict__ wTb2)
{
    const int bid = blockIdx.x;
    if (bid < 1024) {
        __shared__ unsigned short s[64][65];
        const int t = threadIdx.x, lane = t & 63, grp = t >> 6;
        const int hw0 = (bid & 63) * 64, c0 = ((bid >> 6) & 3) * 64, b = bid >> 8;
#pragma unroll
        for (int j = 0; j < 16; ++j) {
            int cc = grp * 16 + j;
            float v = x[((size_t)(b * 256 + c0 + cc)) * HW + hw0 + lane];
            s[cc][lane] = (unsigned short)f2bf(v);
        }
        __syncthreads();
#pragma unroll
        for (int j = 0; j < 16; ++j) {
            int hw2 = grp * 16 + j;
            xT[((size_t)b * HW + hw0 + hw2) * 256 + c0 + lane] = s[lane][hw2];
        }
    } else {
        int e = (bid - 1024) * 256 + threadIdx.x;   // 0..737279
        if (e < 589824) {
            int el = e & 7;
            int lane = (e >> 3) & 63;
            int rg = (e >> 9) & 15;
            int ss = (e >> 13) & 3;
            int j = e >> 15;                        // 0..17
            int o = rg * 16 + (lane & 15);
            int cch = ss * 32 + (lane >> 4) * 8 + el;
            int dg = j / 9, tap = j - dg * 9;
            a2r[e] = f2bf(weight[o * 2304 + (dg * 128 + cch) * 9 + tap]);
        } else {
            int e2 = e - 589824;                    // 0..147455
            int el = e2 & 7;
            int lane = (e2 >> 3) & 63;
            int mi2 = (e2 >> 9) & 3;
            int c = e2 >> 11;                       // 0..71
            int o = mi2 * 16 + (lane & 15);
            int k = c * 32 + ((lane >> 4) << 3) + el;
            int tap = k >> 8, ch = k & 255;
            wTb2[e2] = (o < 54) ? f2bf(w_off[(o * 256 + ch) * 9 + tap]) : (short)0;
        }
    }
}

// ---------------------------------------------------------------------------
// Kernel 2 (k_fused): om-GEMM + plan + sampling + deformable GEMM, fully
// fused. 512 thr / 8 waves, 32 px x 256 m per block, grid 512 = 2/CU.
// Phase 1 (om): M=64(ch) x N=32(px) x K=2304 GEMM for THIS block's pixels.
//   8 waves = 4 m-tiles x 2 n-tiles; B staged into the shared Bs double
//   buffer (4 K-chunks = 8 KB/group, 18 groups); A direct from L2 (wTb2
//   fragment-contiguous). Single-reg-buffer loads issued after the
//   consuming MFMA (R7 lesson: no runtime-selected array refs).
// Phase 2: om -> LDS omS[64][32]; plan (sigmoid/bilinear) -> PlnW/PlnI LDS.
// Phase 3: main loop = R9 structure unchanged (A direct from a2r, gathers,
//   pack to Bs, 16 MFMA/wave/iter, 18 iters).
// Eliminates k_omgemm, om2p (16.7 MB HBM round-trip), and one launch gap.
// LDS: Bs 16 KB + omS 8 KB + Pln 18 KB = 42 KB -> 2 blocks/CU.
// ---------------------------------------------------------------------------
__global__ __launch_bounds__(512, 4) void k_fused(
    const short* __restrict__ A2r, const short* __restrict__ wTb2,
    const unsigned short* __restrict__ xT, const float* __restrict__ b_off,
    const float* __restrict__ bias, float* __restrict__ out)
{
    __shared__ short Bs[2][4][32 * 32];    // 16 KB (om staging + main B)
    __shared__ float omS[64][32];          //  8 KB
    __shared__ float4 PlnW[18][32];        //  9 KB
    __shared__ int4   PlnI[18][32];        //  9 KB
    const int t = threadIdx.x;
    const int wid = __builtin_amdgcn_readfirstlane(t >> 6);  // 0..7
    const int lane = t & 63;
    const int quad = lane >> 4, l16 = lane & 15;
    const int wr = wid;                     // main loop: 8 m-slices of 32

    // XCD swizzle: 512 blocks, 8 XCDs, 64 contiguous bn per XCD.
    const int lin = blockIdx.x;
    const int bn = ((lin & 7) << 6) | (lin >> 3);

    const int n0 = bn * 32, b = n0 >> 12;
    const unsigned short* xb16 = xT + (size_t)b * HW * 256;
    const char* xbb = (const char*)xb16;
    const int px = t >> 4;          // 0..31 (main): pixel this thread samples
    const int cc = (t >> 2) & 3;    // main: 32-ch chunk within K=128 tap
    const int q8 = (t & 3) * 8;     // main: 8-ch granule within chunk

    // ---------------- Phase 1: om GEMM ----------------
    const int qo  = t >> 7;                 // om: chunk-slot 0..3
    const int px2 = (t >> 2) & 31;          // om: pixel 0..31
    const int ksh2 = (t & 3) * 8;           // om: 8-ch granule
    const int nn2 = n0 + px2;
    const int ph = (nn2 & 4095) >> 6, pw_ = nn2 & 63;
    const int bsw2 = ((t & 3) ^ ((px2 >> 1) & 3)) * 8;
    const int mi2 = wid & 3, ni2 = wid >> 2;
    const short* AwOm = wTb2 + mi2 * 512 + lane * 8;

    f32x4 accOm = (f32x4){0.f, 0.f, 0.f, 0.f};
    uint4 arOm[4];
    uint4 gv;

    auto omload = [&](int gi) -> uint4 {
        const int c = gi * 4 + qo;
        const int tap = c >> 3, c0 = (c & 7) * 32;
        const int hh = ph + tap / 3 - 1, ww = pw_ + tap % 3 - 1;
        uint4 bv = {0u, 0u, 0u, 0u};
        if (hh >= 0 && hh < 64 && ww >= 0 && ww < 64)
            bv = *(const uint4*)(xb16 + (size_t)(hh * 64 + ww) * 256 + c0 + ksh2);
        return bv;
    };
    auto aloadOm = [&](int gi) {
#pragma unroll
        for (int q = 0; q < 4; ++q)
            arOm[q] = *(const uint4*)(AwOm + (size_t)(gi * 4 + q) * 2048);
    };

    gv = omload(0);
    *(uint4*)&Bs[0][qo][px2 * 32 + bsw2] = gv;
    aloadOm(0);

#pragma unroll 2
    for (int gi = 0; gi < 18; ++gi) {
        const int p = gi & 1;
        __syncthreads();
        if (gi + 1 < 18) gv = omload(gi + 1);
        __builtin_amdgcn_sched_barrier(0);
#pragma unroll
        for (int q = 0; q < 4; ++q) {
            const int row = ni2 * 16 + l16;
            bf16x8 bq = *(const bf16x8*)&Bs[p][q][row * 32 + (quad ^ ((row >> 1) & 3)) * 8];
            accOm = __builtin_amdgcn_mfma_f32_16x16x32_bf16(
                *(const bf16x8*)&arOm[q], bq, accOm, 0, 0, 0);
        }
        if (gi + 1 < 18) {
            *(uint4*)&Bs[1 - p][qo][px2 * 32 + bsw2] = gv;
            aloadOm(gi + 1);
        }
    }
    __syncthreads();
    {   // om C/D: col = lane&15 (px within n-tile), row = (lane>>4)*4 + r
        const int mrow = mi2 * 16 + (lane >> 4) * 4;
        const int pcol = ni2 * 16 + l16;
#pragma unroll
        for (int rr = 0; rr < 4; ++rr)
            omS[mrow + rr][pcol] = accOm[rr];
    }
    __syncthreads();

    // ---------------- Phase 2: plan ----------------
    for (int s = wid; s < 18; s += 8) {
        if (lane < 32) {
            const int nn = n0 + lane;
            const int dg = s >= 9 ? 1 : 0, tap = s - dg * 9;
            const int hh = (nn >> 6) & 63, ww2 = nn & 63;
            const int cdy = dg * 18 + tap, cdx = cdy + 9, cms = 36 + dg * 9 + tap;
            float dy = b_off[cdy] + omS[cdy][lane];
            float dx = b_off[cdx] + omS[cdx][lane];
            float ms = b_off[cms] + omS[cms][lane];
            ms = 1.f / (1.f + __expf(-ms));
            float py = dy + (float)(hh + tap / 3 - 1);
            float qx = dx + (float)(ww2 + tap % 3 - 1);
            float y0f = floorf(py), x0f = floorf(qx);
            float wy1 = py - y0f, wx1 = qx - x0f;
            float wy0 = 1.f - wy1, wx0 = 1.f - wx1;
            int y0 = (int)y0f, x0 = (int)x0f;
            int y1 = y0 + 1, x1 = x0 + 1;
            bool vy0 = (y0 >= 0) & (y0 < 64), vy1 = (y1 >= 0) & (y1 < 64);
            bool vx0 = (x0 >= 0) & (x0 < 64), vx1 = (x1 >= 0) & (x1 < 64);
            int cy0 = min(max(y0, 0), 63), cy1 = min(max(y1, 0), 63);
            int cx0 = min(max(x0, 0), 63), cx1 = min(max(x1, 0), 63);
            float4 wv;
            wv.x = (vy0 && vx0) ? wy0 * wx0 * ms : 0.f;
            wv.y = (vy0 && vx1) ? wy0 * wx1 * ms : 0.f;
            wv.z = (vy1 && vx0) ? wy1 * wx0 * ms : 0.f;
            wv.w = (vy1 && vx1) ? wy1 * wx1 * ms : 0.f;
            int4 iv = make_int4((cy0 * 64 + cx0) << 9, (cy0 * 64 + cx1) << 9,
                                (cy1 * 64 + cx0) << 9, (cy1 * 64 + cx1) << 9);
            PlnW[s][lane] = wv;
            PlnI[s][lane] = iv;
        }
    }
    __syncthreads();

    // ---------------- Phase 3: main fused loop (R9 unchanged) ----------------
    const short* Aw = A2r + (size_t)(wr * 2) * 512 + lane * 8;

    f32x4 acc[2][2];
#pragma unroll
    for (int i = 0; i < 2; ++i)
#pragma unroll
        for (int j = 0; j < 2; ++j) acc[i][j] = (f32x4){0.f, 0.f, 0.f, 0.f};

    float4 pw[2];
    int4 pi[2];
    uint4 g[4];
    uint4 ar[8];

    auto pwload = [&](int S) { pw[S & 1] = PlnW[S][px]; };
    auto piload = [&](int S) { pi[S & 1] = PlnI[S][px]; };
    auto gather = [&](int j) {
        const int cb = ((j >= 9 ? 128 : 0) + cc * 32 + q8) * 2;
        const int4 i4 = pi[j & 1];
        g[0] = *(const uint4*)(xbb + i4.x + cb);
        g[1] = *(const uint4*)(xbb + i4.y + cb);
        g[2] = *(const uint4*)(xbb + i4.z + cb);
        g[3] = *(const uint4*)(xbb + i4.w + cb);
    };
    auto aload = [&](int j) {
#pragma unroll
        for (int ss = 0; ss < 4; ++ss)
#pragma unroll
            for (int mi = 0; mi < 2; ++mi)
                ar[ss * 2 + mi] =
                    *(const uint4*)(Aw + (size_t)(j * 4 + ss) * 8192 + mi * 512);
    };
    const int bsw = ((t & 3) ^ ((px >> 1) & 3)) * 8;  // swizzled WRITE granule
    auto packwrite = [&](int j, int buf) {
        const float4 w4 = pw[j & 1];
        float a0 = w4.x * blo(g[0].x) + w4.y * blo(g[1].x) + w4.z * blo(g[2].x) + w4.w * blo(g[3].x);
        float a1 = w4.x * bhi(g[0].x) + w4.y * bhi(g[1].x) + w4.z * bhi(g[2].x) + w4.w * bhi(g[3].x);
        float a2v = w4.x * blo(g[0].y) + w4.y * blo(g[1].y) + w4.z * blo(g[2].y) + w4.w * blo(g[3].y);
        float a3 = w4.x * bhi(g[0].y) + w4.y * bhi(g[1].y) + w4.z * bhi(g[2].y) + w4.w * bhi(g[3].y);
        float a4 = w4.x * blo(g[0].z) + w4.y * blo(g[1].z) + w4.z * blo(g[2].z) + w4.w * blo(g[3].z);
        float a5 = w4.x * bhi(g[0].z) + w4.y * bhi(g[1].z) + w4.z * bhi(g[2].z) + w4.w * bhi(g[3].z);
        float a6 = w4.x * blo(g[0].w) + w4.y * blo(g[1].w) + w4.z * blo(g[2].w) + w4.w * blo(g[3].w);
        float a7 = w4.x * bhi(g[0].w) + w4.y * bhi(g[1].w) + w4.z * bhi(g[2].w) + w4.w * bhi(g[3].w);
        uint4 o;
        o.x = cvtpk(a0, a1); o.y = cvtpk(a2v, a3);
        o.z = cvtpk(a4, a5); o.w = cvtpk(a6, a7);
        *(uint4*)&Bs[buf][cc][px * 32 + bsw] = o;
    };
    auto mfmaPhase = [&](int p) {
#pragma unroll
        for (int ss = 0; ss < 4; ++ss) {
            bf16x8 bfr[2];
#pragma unroll
            for (int ni = 0; ni < 2; ++ni) {
                const int row = ni * 16 + l16;
                bfr[ni] = *(const bf16x8*)&Bs[p][ss][row * 32 + (quad ^ ((row >> 1) & 3)) * 8];
            }
#pragma unroll
            for (int mi = 0; mi < 2; ++mi) {
                bf16x8 af = *(const bf16x8*)&ar[ss * 2 + mi];
#pragma unroll
                for (int ni = 0; ni < 2; ++ni)
                    acc[mi][ni] = __builtin_amdgcn_mfma_f32_16x16x32_bf16(
                        af, bfr[ni], acc[mi][ni], 0, 0, 0);
            }
        }
    };

    // prologue: tap 0 packed into Bs[0]; A for tap 0 in ar; plans for 0/1.
    pwload(0);
    piload(0);
    gather(0);
    aload(0);
    packwrite(0, 0);
    pwload(1);
    piload(1);

#pragma unroll 2
    for (int i = 0; i < 18; ++i) {
        const int p = i & 1;
        __syncthreads();
        if (i + 1 < 18) gather(i + 1);       // reads pi[(i+1)&1] (1 iter old)
        if (i + 2 < 18) { pwload(i + 2); piload(i + 2); }
        __builtin_amdgcn_sched_barrier(0);   // pin: gathers/plans issued first
        mfmaPhase(p);                        // consumes ar (tap i), Bs[p]
        if (i + 1 < 18) aload(i + 1);        // overwrite ar AFTER MFMA reads
        if (i + 1 < 18) packwrite(i + 1, 1 - p);   // uses pw[(i+1)&1], g
    }

    const int m0 = wr * 32;
#pragma unroll
    for (int mi = 0; mi < 2; ++mi)
#pragma unroll
        for (int ni = 0; ni < 2; ++ni) {
            int nn = n0 + ni * 16 + l16;
            int bidx = nn >> 12, hw = nn & 4095;
            float* op = out + (size_t)bidx * 256 * 4096 + hw;
#pragma unroll
            for (int r = 0; r < 4; ++r) {
                int m = m0 + mi * 16 + quad * 4 + r;
                op[(size_t)m * 4096] = acc[mi][ni][r] + bias[m];
            }
        }
}

// ---------------------------------------------------------------------------
extern "C" void kernel_launch(void* const* d_in, const int* in_sizes, int n_in,
                              void* d_out, int out_size, void* d_ws, size_t ws_size,
                              hipStream_t stream)
{
    const float* x      = (const float*)d_in[0];
    const float* w_off  = (const float*)d_in[1];
    const float* b_off  = (const float*)d_in[2];
    const float* weight = (const float*)d_in[3];
    const float* bias   = (const float*)d_in[4];
    float* out = (float*)d_out;
    char* ws = (char*)d_ws;

    // ws layout (9,863,168 B used):
    unsigned short* xT   = (unsigned short*)(ws);           //  8,388,608
    short*          a2r  = (short*)(ws + 8388608);          //  1,179,648
    short*          wTb2 = (short*)(ws + 9568256);          //    294,912

    hipLaunchKernelGGL(k_pre, dim3(3904), dim3(256), 0, stream,
                       x, weight, w_off, xT, a2r, wTb2);
    hipLaunchKernelGGL(k_fused, dim3(512), dim3(512), 0, stream,
                       a2r, wTb2, xT, b_off, bias, out);
}